// Round 6
// baseline (20.021 us; speedup 1.0000x reference)
//
#include <hip/hip_runtime.h>
#include <math.h>

// NN-MSE (one-directional Chamfer) loss, 2 dispatches (R3 structure), with a
// register/readlane inner loop instead of LDS-broadcast (R5 post-mortem:
// LDS law 12cyc/ds_read_b128 made R3 LDS-bound at ~10us; readlane moves the
// target broadcast to the VALU/SALU path -> ~5us VALU-bound floor).
//
//  k1: 256 blocks (16 segs x 16 src-chunks), 512 thr = 8 waves.
//      Targets staged once in LDS premultiplied as (-2x,-2y,-2z,|t|^2);
//      each wave owns a 256-target slice, loads it 64-at-a-time into per-lane
//      VGPRs (stride-16B ds_read_b128), then broadcasts each target to all
//      lanes via v_readlane (SGPR operand to v_fma). Each lane owns P=2
//      sources -> per 2 targets: 8 readlane + 12 fma + 2 min3.
//  k2: one tiny block sums the 256 block partials -> loss.

#define THREADS 512      // 8 waves
#define NW 8
#define P 2
#define SRC_BLK 128      // 64 lanes * P

__device__ __forceinline__ float rl(float v, int j) {
    return __int_as_float(__builtin_amdgcn_readlane(__float_as_int(v), j));
}

__global__ __launch_bounds__(THREADS)
void nn_full_kernel(const float* __restrict__ coord,
                    const float* __restrict__ coord_t,
                    const float* __restrict__ Rm,
                    const float* __restrict__ tv,
                    float* __restrict__ ws,
                    int S, int NSC) {
    extern __shared__ char smem_raw[];
    float4* tile = (float4*)smem_raw;                       // S float4 (32KB)
    float*  part = (float*)(smem_raw + (size_t)S * 16);     // NW*64*P floats
    float*  wsum = part + NW * 64 * P;                      // 2 floats

    const int tid  = threadIdx.x;
    const int bid  = blockIdx.x;
    const int b    = bid / NSC;
    const int sc   = bid - b * NSC;
    const int w    = tid >> 6;
    const int lane = tid & 63;

    // ---- stage ALL S targets as (-2x,-2y,-2z,|t|^2); 4 points/thread ----
    {
        const float* tb = coord_t + (size_t)b * S * 3;
        for (int base = tid * 4; base < S; base += THREADS * 4) {
            const float4* g4 = reinterpret_cast<const float4*>(tb + (size_t)base * 3);
            const float4 q0 = g4[0], q1 = g4[1], q2 = g4[2];
            const float px[4] = {q0.x, q0.w, q1.z, q2.y};
            const float py[4] = {q0.y, q1.x, q1.w, q2.z};
            const float pz[4] = {q0.z, q1.y, q2.x, q2.w};
            #pragma unroll
            for (int k = 0; k < 4; ++k) {
                const float x = px[k], y = py[k], z = pz[k];
                tile[base + k] = make_float4(-2.f*x, -2.f*y, -2.f*z,
                                             x*x + y*y + z*z);
            }
        }
    }

    // ---- rigid transform params (block-uniform) ----
    const float* Rb = Rm + (size_t)b * 9;
    const float r00=Rb[0], r01=Rb[1], r02=Rb[2];
    const float r10=Rb[3], r11=Rb[4], r12=Rb[5];
    const float r20=Rb[6], r21=Rb[7], r22=Rb[8];
    const float t0=tv[3*b], t1=tv[3*b+1], t2=tv[3*b+2];

    // ---- this lane's P=2 source points, transformed ----
    float TX[P], TY[P], TZ[P], SN[P], best[P];
    {
        const float* sp = coord + ((size_t)b * S + (size_t)sc * SRC_BLK + lane * P) * 3;
        #pragma unroll
        for (int j = 0; j < P; ++j) {
            const float x = sp[3*j], y = sp[3*j+1], z = sp[3*j+2];
            const float sx = __builtin_fmaf(r00,x,__builtin_fmaf(r01,y,__builtin_fmaf(r02,z,t0)));
            const float sy = __builtin_fmaf(r10,x,__builtin_fmaf(r11,y,__builtin_fmaf(r12,z,t1)));
            const float sz = __builtin_fmaf(r20,x,__builtin_fmaf(r21,y,__builtin_fmaf(r22,z,t2)));
            TX[j]=sx; TY[j]=sy; TZ[j]=sz;
            SN[j]=sx*sx + sy*sy + sz*sz;
            best[j] = 3.0e38f;
        }
    }

    __syncthreads();

    // ---- main loop: wave w scans its S/NW targets via readlane broadcast ----
    const int mPer  = S / NW;                 // 256
    const int mbase = w * mPer;
    const int nch   = mPer / 64;              // 4 chunks of 64 targets
    for (int c = 0; c < nch; ++c) {
        const float4 tch = tile[mbase + c * 64 + lane];   // per-lane target
        #pragma unroll
        for (int j = 0; j < 64; j += 2) {
            const float tx0 = rl(tch.x, j),   ty0 = rl(tch.y, j);
            const float tz0 = rl(tch.z, j),   tn0 = rl(tch.w, j);
            const float tx1 = rl(tch.x, j+1), ty1 = rl(tch.y, j+1);
            const float tz1 = rl(tch.z, j+1), tn1 = rl(tch.w, j+1);
            const float a00 = __builtin_fmaf(TX[0], tx0,
                              __builtin_fmaf(TY[0], ty0,
                              __builtin_fmaf(TZ[0], tz0, tn0)));
            const float a01 = __builtin_fmaf(TX[0], tx1,
                              __builtin_fmaf(TY[0], ty1,
                              __builtin_fmaf(TZ[0], tz1, tn1)));
            const float a10 = __builtin_fmaf(TX[1], tx0,
                              __builtin_fmaf(TY[1], ty0,
                              __builtin_fmaf(TZ[1], tz0, tn0)));
            const float a11 = __builtin_fmaf(TX[1], tx1,
                              __builtin_fmaf(TY[1], ty1,
                              __builtin_fmaf(TZ[1], tz1, tn1)));
            best[0] = fminf(fminf(best[0], a00), a01);    // v_min3
            best[1] = fminf(fminf(best[1], a10), a11);    // v_min3
        }
    }

    // ---- fold |s|^2; min across 8 waves; clamp; block sum ----
    #pragma unroll
    for (int j = 0; j < P; ++j)
        part[tid * P + j] = best[j] + SN[j];
    __syncthreads();

    float v = 0.0f;
    if (tid < SRC_BLK) {
        float mn = part[tid];                        // stride-1, conflict-free
        #pragma unroll
        for (int ww = 1; ww < NW; ++ww)
            mn = fminf(mn, part[ww * SRC_BLK + tid]);
        v = fmaxf(mn, 0.0f);
    }
    if (tid < 128) {
        #pragma unroll
        for (int off = 32; off > 0; off >>= 1) v += __shfl_down(v, off, 64);
        if ((tid & 63) == 0) wsum[tid >> 6] = v;
    }
    __syncthreads();
    if (tid == 0) ws[bid] = wsum[0] + wsum[1];
}

__global__ __launch_bounds__(256)
void final_kernel(const float* __restrict__ partial, int n,
                  float* __restrict__ out, float scale) {
    float v = (threadIdx.x < n) ? partial[threadIdx.x] : 0.0f;
    #pragma unroll
    for (int off = 32; off > 0; off >>= 1) v += __shfl_down(v, off, 64);
    __shared__ float sm[4];
    if ((threadIdx.x & 63) == 0) sm[threadIdx.x >> 6] = v;
    __syncthreads();
    if (threadIdx.x == 0) out[0] = (sm[0] + sm[1] + sm[2] + sm[3]) * scale;
}

extern "C" void kernel_launch(void* const* d_in, const int* in_sizes, int n_in,
                              void* d_out, int out_size, void* d_ws, size_t ws_size,
                              hipStream_t stream) {
    const float* coord   = (const float*)d_in[0];
    const float* coord_t = (const float*)d_in[1];
    const float* Rm      = (const float*)d_in[2];
    const float* tv      = (const float*)d_in[3];

    const int B = in_sizes[2] / 9;            // R is [B,3,3]
    const int S = in_sizes[0] / (3 * B);      // coord is [B*S,3]
    const int NSC = S / SRC_BLK;              // 16
    const int nblk = B * NSC;                 // 256

    float* ws  = (float*)d_ws;
    float* out = (float*)d_out;

    const size_t smem = (size_t)S * 16 + NW * 64 * P * 4 + 2 * 4;

    nn_full_kernel<<<nblk, THREADS, smem, stream>>>(
        coord, coord_t, Rm, tv, ws, S, NSC);

    final_kernel<<<1, 256, 0, stream>>>(
        ws, nblk, out, 1.0f / ((float)B * (float)S));
}

// Round 7
// 18.200 us; speedup vs baseline: 1.1000x; 1.1000x over previous
//
#include <hip/hip_runtime.h>
#include <math.h>

// NN-MSE (one-directional Chamfer) loss, 2 dispatches.
// R6 post-mortem: readlane broadcast is a VALU op (5.5 instr/eval) - regressed.
// R7: target broadcast moved to the SCALAR pipe. Targets are wave-uniform, so
// each wave reads its 256-target slice with s_load (uniform address derived
// from readfirstlane'd wave id), keeping targets in SGPRs. v_fma takes the
// target component as its single allowed SGPR operand. No LDS tile, no
// staging barrier. Per 2 targets (P=2): 6 tn + 12 fma + 2 min3 = 20 VALU for
// 256 lane-evals -> ~4.3us VALU floor across 4 SIMDs/CU; LDS pipe idle.
//
// d2 = |s|^2 + (|t|^2 - 2 s.t) ; source side premultiplied: TXp = -2*sx etc.
// acc = fma(tx,TXp, fma(ty,TYp, fma(tz,TZp, tn))), tn = tx^2+ty^2+tz^2.

#define THREADS 512      // 8 waves
#define NW 8
#define P 2
#define SRC_BLK 128      // 64 lanes * P
#define CHUNK 16         // targets fetched per scalar-load batch (48 floats)

__global__ __launch_bounds__(THREADS)
void nn_full_kernel(const float* __restrict__ coord,
                    const float* __restrict__ coord_t,
                    const float* __restrict__ Rm,
                    const float* __restrict__ tv,
                    float* __restrict__ ws,
                    int S, int NSC) {
    __shared__ float part[NW * 64 * P];
    __shared__ float wsum[2];

    const int tid  = threadIdx.x;
    const int bid  = blockIdx.x;
    const int b    = bid / NSC;
    const int sc   = bid - b * NSC;
    const int lane = tid & 63;

    // ---- rigid transform params (block-uniform -> s_load) ----
    const float* Rb = Rm + (size_t)b * 9;
    const float r00=Rb[0], r01=Rb[1], r02=Rb[2];
    const float r10=Rb[3], r11=Rb[4], r12=Rb[5];
    const float r20=Rb[6], r21=Rb[7], r22=Rb[8];
    const float t0=tv[3*b], t1=tv[3*b+1], t2=tv[3*b+2];

    // ---- this lane's P=2 source points: transform, premultiply by -2 ----
    float TXp[P], TYp[P], TZp[P], SN[P], best[P];
    {
        const float* sp = coord + ((size_t)b * S + (size_t)sc * SRC_BLK + lane * P) * 3;
        #pragma unroll
        for (int j = 0; j < P; ++j) {
            const float x = sp[3*j], y = sp[3*j+1], z = sp[3*j+2];
            const float sx = __builtin_fmaf(r00,x,__builtin_fmaf(r01,y,__builtin_fmaf(r02,z,t0)));
            const float sy = __builtin_fmaf(r10,x,__builtin_fmaf(r11,y,__builtin_fmaf(r12,z,t1)));
            const float sz = __builtin_fmaf(r20,x,__builtin_fmaf(r21,y,__builtin_fmaf(r22,z,t2)));
            TXp[j] = -2.0f * sx;  TYp[j] = -2.0f * sy;  TZp[j] = -2.0f * sz;
            SN[j]  = sx*sx + sy*sy + sz*sz;
            best[j] = 3.0e38f;
        }
    }

    // ---- main loop: wave w scans its S/NW-target slice via SCALAR loads ----
    const int w_u = __builtin_amdgcn_readfirstlane(tid >> 6);   // wave id, SGPR
    const int mPer = S / NW;                                    // 256
    const float* tb = coord_t + ((size_t)b * S + (size_t)w_u * mPer) * 3;

    for (int c = 0; c < mPer / CHUNK; ++c) {          // 16 chunks
        const float* cb = tb + c * (CHUNK * 3);       // uniform address
        float f[CHUNK * 3];
        #pragma unroll
        for (int k = 0; k < CHUNK * 3; ++k) f[k] = cb[k];   // -> s_load_dwordx16 x3

        #pragma unroll
        for (int t = 0; t < CHUNK; t += 2) {
            const float tx0 = f[3*t+0], ty0 = f[3*t+1], tz0 = f[3*t+2];
            const float tx1 = f[3*t+3], ty1 = f[3*t+4], tz1 = f[3*t+5];
            const float tn0 = __builtin_fmaf(tz0, tz0,
                              __builtin_fmaf(ty0, ty0, tx0 * tx0));
            const float tn1 = __builtin_fmaf(tz1, tz1,
                              __builtin_fmaf(ty1, ty1, tx1 * tx1));
            const float a00 = __builtin_fmaf(tx0, TXp[0],
                              __builtin_fmaf(ty0, TYp[0],
                              __builtin_fmaf(tz0, TZp[0], tn0)));
            const float a01 = __builtin_fmaf(tx1, TXp[0],
                              __builtin_fmaf(ty1, TYp[0],
                              __builtin_fmaf(tz1, TZp[0], tn1)));
            const float a10 = __builtin_fmaf(tx0, TXp[1],
                              __builtin_fmaf(ty0, TYp[1],
                              __builtin_fmaf(tz0, TZp[1], tn0)));
            const float a11 = __builtin_fmaf(tx1, TXp[1],
                              __builtin_fmaf(ty1, TYp[1],
                              __builtin_fmaf(tz1, TZp[1], tn1)));
            best[0] = fminf(fminf(best[0], a00), a01);   // v_min3
            best[1] = fminf(fminf(best[1], a10), a11);   // v_min3
        }
    }

    // ---- fold |s|^2; min across 8 waves; clamp; block sum ----
    #pragma unroll
    for (int j = 0; j < P; ++j)
        part[tid * P + j] = best[j] + SN[j];
    __syncthreads();

    float v = 0.0f;
    if (tid < SRC_BLK) {
        float mn = part[tid];                        // stride-1, conflict-free
        #pragma unroll
        for (int ww = 1; ww < NW; ++ww)
            mn = fminf(mn, part[ww * SRC_BLK + tid]);
        v = fmaxf(mn, 0.0f);
    }
    if (tid < 128) {
        #pragma unroll
        for (int off = 32; off > 0; off >>= 1) v += __shfl_down(v, off, 64);
        if ((tid & 63) == 0) wsum[tid >> 6] = v;
    }
    __syncthreads();
    if (tid == 0) ws[bid] = wsum[0] + wsum[1];
}

__global__ __launch_bounds__(256)
void final_kernel(const float* __restrict__ partial, int n,
                  float* __restrict__ out, float scale) {
    float v = (threadIdx.x < n) ? partial[threadIdx.x] : 0.0f;
    #pragma unroll
    for (int off = 32; off > 0; off >>= 1) v += __shfl_down(v, off, 64);
    __shared__ float sm[4];
    if ((threadIdx.x & 63) == 0) sm[threadIdx.x >> 6] = v;
    __syncthreads();
    if (threadIdx.x == 0) out[0] = (sm[0] + sm[1] + sm[2] + sm[3]) * scale;
}

extern "C" void kernel_launch(void* const* d_in, const int* in_sizes, int n_in,
                              void* d_out, int out_size, void* d_ws, size_t ws_size,
                              hipStream_t stream) {
    const float* coord   = (const float*)d_in[0];
    const float* coord_t = (const float*)d_in[1];
    const float* Rm      = (const float*)d_in[2];
    const float* tv      = (const float*)d_in[3];

    const int B = in_sizes[2] / 9;            // R is [B,3,3]
    const int S = in_sizes[0] / (3 * B);      // coord is [B*S,3]
    const int NSC = S / SRC_BLK;              // 16
    const int nblk = B * NSC;                 // 256

    float* ws  = (float*)d_ws;
    float* out = (float*)d_out;

    nn_full_kernel<<<nblk, THREADS, 0, stream>>>(
        coord, coord_t, Rm, tv, ws, S, NSC);

    final_kernel<<<1, 256, 0, stream>>>(
        ws, nblk, out, 1.0f / ((float)B * (float)S));
}

// Round 8
// 12.246 us; speedup vs baseline: 1.6348x; 1.4862x over previous
//
#include <hip/hip_runtime.h>
#include <math.h>

// NN-MSE (one-directional Chamfer) via MFMA, 2 dispatches.
//
// d2(n,m) = |s_n|^2 + (|t_m|^2 - 2 s_n.t_m). The parenthesized term for a
// 32x32 (source,target) tile is ONE v_mfma_f32_32x32x16_f16:
//   A (32 src x K16), lane l: row=l&31, k=8*(l>>5)+j. Lanes<32 hold
//     [shx,shy,shz, slx,sly,slz, 1, 1]  (fp16 hi/lo split of transformed src)
//   lanes>=32: zeros (k8..15 unused).
//   B (K16 x 32 tgt), lane l: col=l&31: [uhx,uhy,uhz,uhx,uhy,uhz,TNh,TNl]
//     where u = -2*t (fp16), TN = |t|^2 fp32 split into fp16 hi+lo.
//   => acc(row,col) = (sh+sl).uh + TN ~= -2 s.t + |t|^2   (err ~ s.ul ~ 3e-3)
// One ds_read_b128/wave per 1024 evals -> LDS pipe ~1.3us/CU (was 10.2).
// C/D layout (verified m74/m101): col=lane&31, row=(reg&3)+8*(reg>>2)+4*(lane>>5).
//
// k1: 256 blocks x 512 thr (8 waves = 4 src-tiles x 2 target-halves).
//     Per-source min: 16 v_min3 per 2 tiles in regs, then shfl_xor(1,2) col
//     prereduce, part[] (stride 18, 2-way max) + combine + block sum -> ws.
// k2: sum 256 partials -> loss.

#define THREADS 512
#define NW 8
#define SRC_BLK 128
#define PART_STRIDE 18

typedef __attribute__((ext_vector_type(8))) _Float16 half8;
typedef __attribute__((ext_vector_type(16))) float f32x16;

__device__ __forceinline__ unsigned short f16b(float x) {
    _Float16 hv = (_Float16)x;
    return __builtin_bit_cast(unsigned short, hv);
}
__device__ __forceinline__ float f16tof(unsigned short u) {
    return (float)__builtin_bit_cast(_Float16, u);
}

__global__ __launch_bounds__(THREADS)
void nn_mfma_kernel(const float* __restrict__ coord,
                    const float* __restrict__ coord_t,
                    const float* __restrict__ Rm,
                    const float* __restrict__ tv,
                    float* __restrict__ ws,
                    int S, int NSC) {
    __shared__ uint4 Bfrag[2048];                 // 32 KB: one 16B entry/target
    __shared__ float part[128 * PART_STRIDE];     // 9 KB, padded stride
    __shared__ float SN_lds[128];
    __shared__ float wsum[2];

    const int tid  = threadIdx.x;
    const int bid  = blockIdx.x;
    const int b    = bid / NSC;
    const int sc   = bid - b * NSC;
    const int w    = tid >> 6;
    const int lane = tid & 63;
    const int col  = lane & 31;
    const int kh   = lane >> 5;
    const int wsrc = w >> 1;      // src-tile 0..3
    const int h    = w & 1;       // target half 0..1

    // ---- stage B fragments: one uint4 (8 fp16 k-slots) per target ----
    {
        const float* tb = coord_t + (size_t)b * S * 3;
        for (int g = tid; g < S; g += THREADS) {
            const float tx = tb[3*g], ty = tb[3*g+1], tz = tb[3*g+2];
            const float TN = __builtin_fmaf(tz, tz, __builtin_fmaf(ty, ty, tx*tx));
            const unsigned uhx = f16b(-2.f*tx), uhy = f16b(-2.f*ty), uhz = f16b(-2.f*tz);
            const unsigned TNh = f16b(TN);
            const unsigned TNl = f16b(TN - f16tof((unsigned short)TNh));
            uint4 wv;
            wv.x = uhx | (uhy << 16);
            wv.y = uhz | (uhx << 16);
            wv.z = uhy | (uhz << 16);
            wv.w = TNh | (TNl << 16);
            Bfrag[g] = wv;
        }
    }

    // ---- A fragment: transformed source, fp16 hi/lo split ----
    half8 afrag;
    #pragma unroll
    for (int i = 0; i < 8; ++i) afrag[i] = (_Float16)0.0f;
    {
        const float* Rb = Rm + (size_t)b * 9;
        const float r00=Rb[0], r01=Rb[1], r02=Rb[2];
        const float r10=Rb[3], r11=Rb[4], r12=Rb[5];
        const float r20=Rb[6], r21=Rb[7], r22=Rb[8];
        const float t0=tv[3*b], t1=tv[3*b+1], t2=tv[3*b+2];

        const float* sp = coord + ((size_t)b*S + (size_t)sc*SRC_BLK + wsrc*32 + col) * 3;
        const float x = sp[0], y = sp[1], z = sp[2];
        const float sx = __builtin_fmaf(r00,x,__builtin_fmaf(r01,y,__builtin_fmaf(r02,z,t0)));
        const float sy = __builtin_fmaf(r10,x,__builtin_fmaf(r11,y,__builtin_fmaf(r12,z,t1)));
        const float sz = __builtin_fmaf(r20,x,__builtin_fmaf(r21,y,__builtin_fmaf(r22,z,t2)));
        const float SN = __builtin_fmaf(sz, sz, __builtin_fmaf(sy, sy, sx*sx));
        if (h == 0 && kh == 0) SN_lds[wsrc*32 + col] = SN;
        if (kh == 0) {
            const _Float16 shx = (_Float16)sx, shy = (_Float16)sy, shz = (_Float16)sz;
            const _Float16 slx = (_Float16)(sx - (float)shx);
            const _Float16 sly = (_Float16)(sy - (float)shy);
            const _Float16 slz = (_Float16)(sz - (float)shz);
            afrag[0] = shx; afrag[1] = shy; afrag[2] = shz;
            afrag[3] = slx; afrag[4] = sly; afrag[5] = slz;
            afrag[6] = (_Float16)1.0f; afrag[7] = (_Float16)1.0f;
        }
    }

    __syncthreads();

    // ---- main loop: 32 target tiles per wave, 2 per iteration ----
    f32x16 zf, mn;
    #pragma unroll
    for (int r = 0; r < 16; ++r) { zf[r] = 0.0f; mn[r] = 1e30f; }

    const uint4* Bp = &Bfrag[h*1024 + col];
    const int nit = S >> 7;                       // 16
    for (int it = 0; it < nit; ++it) {
        const half8 b0 = *reinterpret_cast<const half8*>(Bp + it*64);
        const half8 b1 = *reinterpret_cast<const half8*>(Bp + it*64 + 32);
        const f32x16 aA = __builtin_amdgcn_mfma_f32_32x32x16_f16(afrag, b0, zf, 0, 0, 0);
        const f32x16 aB = __builtin_amdgcn_mfma_f32_32x32x16_f16(afrag, b1, zf, 0, 0, 0);
        #pragma unroll
        for (int r = 0; r < 16; ++r)
            mn[r] = fminf(fminf(mn[r], aA[r]), aB[r]);    // v_min3
    }

    // ---- col prereduce (groups of 4) + write to padded part[] ----
    #pragma unroll
    for (int r = 0; r < 16; ++r) {
        float v = mn[r];
        v = fminf(v, __shfl_xor(v, 1, 64));
        v = fminf(v, __shfl_xor(v, 2, 64));
        if ((col & 3) == 0) {
            const int row = (r & 3) + 8*(r >> 2) + 4*kh;
            part[(wsrc*32 + row)*PART_STRIDE + h*8 + (col >> 2)] = v;
        }
    }
    __syncthreads();

    // ---- combine 16 partials/source, add |s|^2, clamp, block sum ----
    float acc = 0.0f;
    if (tid < 128) {
        const float* pp = &part[tid * PART_STRIDE];
        float m = pp[0];
        #pragma unroll
        for (int j = 1; j < 16; ++j) m = fminf(m, pp[j]);
        acc = fmaxf(SN_lds[tid] + m, 0.0f);
        #pragma unroll
        for (int off = 32; off > 0; off >>= 1) acc += __shfl_down(acc, off, 64);
        if ((tid & 63) == 0) wsum[tid >> 6] = acc;
    }
    __syncthreads();
    if (tid == 0) ws[bid] = wsum[0] + wsum[1];
}

__global__ __launch_bounds__(256)
void final_kernel(const float* __restrict__ partial, int n,
                  float* __restrict__ out, float scale) {
    float v = (threadIdx.x < n) ? partial[threadIdx.x] : 0.0f;
    #pragma unroll
    for (int off = 32; off > 0; off >>= 1) v += __shfl_down(v, off, 64);
    __shared__ float sm[4];
    if ((threadIdx.x & 63) == 0) sm[threadIdx.x >> 6] = v;
    __syncthreads();
    if (threadIdx.x == 0) out[0] = (sm[0] + sm[1] + sm[2] + sm[3]) * scale;
}

extern "C" void kernel_launch(void* const* d_in, const int* in_sizes, int n_in,
                              void* d_out, int out_size, void* d_ws, size_t ws_size,
                              hipStream_t stream) {
    const float* coord   = (const float*)d_in[0];
    const float* coord_t = (const float*)d_in[1];
    const float* Rm      = (const float*)d_in[2];
    const float* tv      = (const float*)d_in[3];

    const int B = in_sizes[2] / 9;            // R is [B,3,3]
    const int S = in_sizes[0] / (3 * B);      // coord is [B*S,3]
    const int NSC = S / SRC_BLK;              // 16
    const int nblk = B * NSC;                 // 256

    float* ws  = (float*)d_ws;
    float* out = (float*)d_out;

    nn_mfma_kernel<<<nblk, THREADS, 0, stream>>>(
        coord, coord_t, Rm, tv, ws, S, NSC);

    final_kernel<<<1, 256, 0, stream>>>(
        ws, nblk, out, 1.0f / ((float)B * (float)S));
}